// Round 4
// baseline (351.963 us; speedup 1.0000x reference)
//
#include <hip/hip_runtime.h>
#include <math.h>

typedef unsigned short u16;
typedef __attribute__((ext_vector_type(8))) short short8;
typedef __attribute__((ext_vector_type(4))) float floatx4;
typedef __attribute__((ext_vector_type(4))) short sh4v;

union sh4u { sh4v v; u16 u[4]; };
union sh8u { short8 v; u16 u[8]; };

__device__ __forceinline__ floatx4 mfma16(short8 a, short8 b, floatx4 c) {
  return __builtin_amdgcn_mfma_f32_16x16x32_bf16(a, b, c, 0, 0, 0);
}

__device__ __forceinline__ floatx4 zero4() {
  floatx4 z = {0.f, 0.f, 0.f, 0.f};
  return z;
}

__device__ __forceinline__ u16 f2b(float f) {
  union { float f; unsigned u; } v; v.f = f;
  unsigned u = v.u;
  return (u16)((u + 0x7FFFu + ((u >> 16) & 1u)) >> 16);
}

__device__ __forceinline__ float b2f(u16 u) {
  union { unsigned u; float f; } v; v.u = ((unsigned)u) << 16;
  return v.f;
}

__device__ __forceinline__ float gelu_exact(float x) {
  return 0.5f * x * (1.f + erff(x * 0.70710678118654752440f));
}

__device__ __forceinline__ unsigned pack2(float a, float b) {
  return (unsigned)f2b(a) | ((unsigned)f2b(b) << 16);
}

// truncating pack of two f32 -> two bf16 in one v_perm
__device__ __forceinline__ unsigned permpack(float p0, float p1) {
  return __builtin_amdgcn_perm(__float_as_uint(p1), __float_as_uint(p0), 0x07060302u);
}

// ------------- weight prep: transpose-convert 6 weights + wcT build, one launch -------------
// blocks 0..539: W[K][N] f32 -> W^T[N][K] bf16 (64x64 tiles)
// blocks 540..611: wcT[j][k] = (j<384) ? w_knn[k][j] : w_knn[384+k][j-384]-w_knn[k][j-384]
__global__ __launch_bounds__(256) void tc7_kernel(
    const float* __restrict__ p0, const float* __restrict__ p1,
    const float* __restrict__ p2, const float* __restrict__ p3,
    const float* __restrict__ p4, const float* __restrict__ p5,
    const float* __restrict__ wknn,
    u16* __restrict__ o0, u16* __restrict__ o1, u16* __restrict__ o2,
    u16* __restrict__ o3, u16* __restrict__ o4, u16* __restrict__ o5,
    u16* __restrict__ wcT) {
  __shared__ u16 L[64][66];
  int t = blockIdx.x, tid = threadIdx.x;
  if (t >= 540) {
    t -= 540;                       // 6 k-tiles x 12 j-tiles
    int tk = t / 12, tn = t % 12;
    int k0 = tk * 64, j0 = tn * 64;
#pragma unroll
    for (int i = 0; i < 4; i++) {
      int c = tid + 256 * i;
      int r = c >> 4, c4 = (c & 15) * 4;
      floatx4 v;
      if (j0 < 384) {
        v = *(const floatx4*)(wknn + (size_t)(k0 + r) * 384 + j0 + c4);
      } else {
        floatx4 a = *(const floatx4*)(wknn + (size_t)(384 + k0 + r) * 384 + (j0 - 384) + c4);
        floatx4 b = *(const floatx4*)(wknn + (size_t)(k0 + r) * 384 + (j0 - 384) + c4);
        v = a - b;
      }
      *(unsigned*)&L[r][c4]     = pack2(v[0], v[1]);
      *(unsigned*)&L[r][c4 + 2] = pack2(v[2], v[3]);
    }
    __syncthreads();
#pragma unroll
    for (int i = 0; i < 2; i++) {
      int c = tid + 256 * i;
      int nn = c >> 3, k8 = (c & 7) * 8;
      sh8u pk;
#pragma unroll
      for (int j = 0; j < 8; j++) pk.u[j] = L[k8 + j][nn];
      *(short8*)(wcT + (size_t)(j0 + nn) * 384 + k0 + k8) = pk.v;
    }
    return;
  }
  const float* src; u16* dst; int Kd, Nd, tk, tn;
  if      (t < 108) { src = p0; dst = o0; Kd = 384;  Nd = 1152; tk = t / 18; tn = t % 18; }
  else if (t < 144) { src = p1; dst = o1; Kd = 384;  Nd = 384;  t -= 108; tk = t / 6;  tn = t % 6; }
  else if (t < 216) { src = p2; dst = o2; Kd = 768;  Nd = 384;  t -= 144; tk = t / 6;  tn = t % 6; }
  else if (t < 252) { src = p3; dst = o3; Kd = 384;  Nd = 384;  t -= 216; tk = t / 6;  tn = t % 6; }
  else if (t < 396) { src = p4; dst = o4; Kd = 384;  Nd = 1536; t -= 252; tk = t / 24; tn = t % 24; }
  else              { src = p5; dst = o5; Kd = 1536; Nd = 384;  t -= 396; tk = t / 6;  tn = t % 6; }
  int k0 = tk * 64, n0 = tn * 64;
#pragma unroll
  for (int i = 0; i < 4; i++) {
    int c = tid + 256 * i;
    int r = c >> 4, c4 = (c & 15) * 4;
    floatx4 v = *(const floatx4*)(src + (size_t)(k0 + r) * Nd + n0 + c4);
    *(unsigned*)&L[r][c4]     = pack2(v[0], v[1]);
    *(unsigned*)&L[r][c4 + 2] = pack2(v[2], v[3]);
  }
  __syncthreads();
#pragma unroll
  for (int i = 0; i < 2; i++) {
    int c = tid + 256 * i;
    int nn = c >> 3, k8 = (c & 7) * 8;
    sh8u pk;
#pragma unroll
    for (int j = 0; j < 8; j++) pk.u[j] = L[k8 + j][nn];
    *(short8*)(dst + (size_t)(n0 + nn) * Kd + k0 + k8) = pk.v;
  }
}

// ---------------- LayerNorm (fp32 in -> bf16 out), one wave per row of 384 ----------------
__global__ __launch_bounds__(256) void ln_kernel(const float* __restrict__ x,
                                                 const float* __restrict__ g,
                                                 const float* __restrict__ bia,
                                                 u16* __restrict__ out) {
  int wave = threadIdx.x >> 6, lane = threadIdx.x & 63;
  int row = blockIdx.x * 4 + wave;
  const float* xr = x + (size_t)row * 384;
  float v[6];
  float s = 0.f;
#pragma unroll
  for (int j = 0; j < 6; j++) { v[j] = xr[lane + 64 * j]; s += v[j]; }
#pragma unroll
  for (int off = 32; off > 0; off >>= 1) s += __shfl_xor(s, off);
  float mu = s * (1.f / 384.f);
  float ss = 0.f;
#pragma unroll
  for (int j = 0; j < 6; j++) { float d = v[j] - mu; ss += d * d; }
#pragma unroll
  for (int off = 32; off > 0; off >>= 1) ss += __shfl_xor(ss, off);
  float rstd = rsqrtf(ss * (1.f / 384.f) + 1e-5f);
  u16* orow = out + (size_t)row * 384;
#pragma unroll
  for (int j = 0; j < 6; j++) {
    int d = lane + 64 * j;
    orow[d] = f2b((v[j] - mu) * rstd * g[d] + bia[d]);
  }
}

// ---------------- gemm128: 128x128 tile, BK=64, B pre-transposed ----------------
// EPI: 3 gelu(+bias) -> bf16 | 6 bf16 + V^T scatter + Q pre-scale (qkv only)
template <int EPI>
__global__ __launch_bounds__(256) void gemm128_kernel(
    const u16* __restrict__ A0, const u16* __restrict__ BwT, int N, int K,
    const float* __restrict__ bias, u16* __restrict__ outB,
    u16* __restrict__ outV) {
  __shared__ u16 As[128][72];
  __shared__ u16 Bs[128][72];
  int tid = threadIdx.x;
  int lane = tid & 63, wave = tid >> 6, quad = lane >> 4, l16 = lane & 15;
  int n0 = blockIdx.x * 128, m0 = blockIdx.y * 128;
  int wm = (wave >> 1) * 64, wn = (wave & 1) * 64;
  floatx4 acc[4][4];
#pragma unroll
  for (int i = 0; i < 4; i++)
#pragma unroll
    for (int j = 0; j < 4; j++) acc[i][j] = zero4();

  for (int k0 = 0; k0 < K; k0 += 64) {
#pragma unroll
    for (int i = 0; i < 4; i++) {
      int c = tid + 256 * i;
      int row = c >> 3, c8 = (c & 7) * 8;
      *(short8*)&As[row][c8] =
          *(const short8*)(A0 + (size_t)(m0 + row) * K + k0 + c8);
      *(short8*)&Bs[row][c8] =
          *(const short8*)(BwT + (size_t)(n0 + row) * K + k0 + c8);
    }
    __syncthreads();
#pragma unroll
    for (int kh = 0; kh < 2; kh++) {
      short8 af[4], bfr[4];
#pragma unroll
      for (int ti = 0; ti < 4; ti++)
        af[ti] = *(const short8*)&As[wm + ti * 16 + l16][kh * 32 + quad * 8];
#pragma unroll
      for (int tj = 0; tj < 4; tj++)
        bfr[tj] = *(const short8*)&Bs[wn + tj * 16 + l16][kh * 32 + quad * 8];
#pragma unroll
      for (int ti = 0; ti < 4; ti++)
#pragma unroll
        for (int tj = 0; tj < 4; tj++)
          acc[ti][tj] = mfma16(af[ti], bfr[tj], acc[ti][tj]);
    }
    __syncthreads();
  }

#pragma unroll
  for (int ti = 0; ti < 4; ti++)
#pragma unroll
    for (int tj = 0; tj < 4; tj++) {
      int col = n0 + wn + tj * 16 + l16;
      int row0 = m0 + wm + ti * 16 + quad * 4;
      if (EPI == 6) {
        float sc = (col < 384) ? 0.18033688011112042f : 1.f;  // Q * 0.125*log2(e)
        sh4u pk;
#pragma unroll
        for (int r = 0; r < 4; r++) {
          u16 bv = f2b(acc[ti][tj][r] * sc);
          outB[(size_t)(row0 + r) * N + col] = bv;
          pk.u[r] = bv;
        }
        if (col >= 768) {
          int b = row0 >> 11, n = row0 & 2047;
          int hd = col - 768;
          *(sh4v*)(outV + ((size_t)(b * 6 + (hd >> 6)) * 64 + (hd & 63)) * 2048 + n) = pk.v;
        }
      } else {
#pragma unroll
        for (int r = 0; r < 4; r++) {
          float v = gelu_exact(acc[ti][tj][r] + bias[col]);
          outB[(size_t)(row0 + r) * N + col] = f2b(v);
        }
      }
    }
}

// ---------------- gemm64: 64x64 tile, BK=64, high-occupancy for skinny GEMMs ----------------
// EPI: 0 bf16 | 2 +bias -> bf16 | 3 gelu(+bias) -> bf16 | 4 gate -> f32 | 5 +bias+resid -> f32
template <int EPI>
__global__ __launch_bounds__(256) void gemm64_kernel(
    const u16* __restrict__ A0, const u16* __restrict__ A1, int Ksplit,
    const u16* __restrict__ BwT, int N, int K,
    const float* __restrict__ bias,
    float* __restrict__ outF, u16* __restrict__ outB,
    const u16* __restrict__ eA16, const u16* __restrict__ eK16,
    const float* __restrict__ eX) {
  __shared__ u16 As[64][72];
  __shared__ u16 Bs[64][72];
  int tid = threadIdx.x;
  int lane = tid & 63, wave = tid >> 6, quad = lane >> 4, l16 = lane & 15;
  int n0 = blockIdx.x * 64, m0 = blockIdx.y * 64;
  floatx4 acc[4];
#pragma unroll
  for (int i = 0; i < 4; i++) acc[i] = zero4();

  for (int k0 = 0; k0 < K; k0 += 64) {
    const u16* Ap;
    int kk, sA;
    if (k0 < Ksplit) { Ap = A0; kk = k0; sA = Ksplit; }
    else             { Ap = A1; kk = k0 - Ksplit; sA = K - Ksplit; }
#pragma unroll
    for (int i = 0; i < 2; i++) {
      int c = tid + 256 * i;
      int row = c >> 3, c8 = (c & 7) * 8;
      *(short8*)&As[row][c8] =
          *(const short8*)(Ap + (size_t)(m0 + row) * sA + kk + c8);
      *(short8*)&Bs[row][c8] =
          *(const short8*)(BwT + (size_t)(n0 + row) * K + k0 + c8);
    }
    __syncthreads();
#pragma unroll
    for (int kh = 0; kh < 2; kh++) {
      short8 bfr = *(const short8*)&Bs[wave * 16 + l16][kh * 32 + quad * 8];
#pragma unroll
      for (int mt = 0; mt < 4; mt++) {
        short8 af = *(const short8*)&As[mt * 16 + l16][kh * 32 + quad * 8];
        acc[mt] = mfma16(af, bfr, acc[mt]);
      }
    }
    __syncthreads();
  }

  int col = n0 + wave * 16 + l16;
#pragma unroll
  for (int mt = 0; mt < 4; mt++) {
    int row0 = m0 + mt * 16 + quad * 4;
#pragma unroll
    for (int r = 0; r < 4; r++) {
      size_t rc = (size_t)(row0 + r) * N + col;
      float v = acc[mt][r];
      if (EPI == 0) {
        outB[rc] = f2b(v);
      } else if (EPI == 2) {
        outB[rc] = f2b(v + bias[col]);
      } else if (EPI == 3) {
        outB[rc] = f2b(gelu_exact(v + bias[col]));
      } else if (EPI == 4) {
        float gte = 1.f / (1.f + __expf(-(v + bias[col])));
        float fu = (1.f - gte) * b2f(eA16[rc]) + gte * b2f(eK16[rc]);
        outF[rc] = eX[rc] + fu;
      } else if (EPI == 5) {
        outF[rc] = v + bias[col] + eX[rc];
      }
    }
  }
}

// ---------------- attention, S^T form: S^T = K·Q^T, O^T = V^T·P^T ----------------
// grid (32 qblocks, 24 bh), 256 thr. Q pre-scaled by 0.125*log2e -> p = exp2(s).
__global__ __launch_bounds__(256) void attn1_kernel(const u16* __restrict__ qkv,
                                                    const u16* __restrict__ Vt,
                                                    u16* __restrict__ attnpre) {
  __shared__ u16 Ks[2][64][72];   // K tile [key][dim]
  __shared__ u16 Vts[2][64][72];  // V^T tile [dim][key]
  __shared__ u16 Ps[4][16][72];   // per-wave P [qrow][key]
  int tid = threadIdx.x;
  int lane = tid & 63, wave = tid >> 6, quad = lane >> 4, l16 = lane & 15;
  int bh = blockIdx.y, b = bh / 6, h = bh % 6;
  int q0 = blockIdx.x * 64;
  const u16* qbase = qkv + (size_t)b * 2048 * 1152 + h * 64;
  const u16* kbase = qbase + 384;
  const u16* vtb = Vt + (size_t)bh * 64 * 2048;
  int qrow = q0 + wave * 16 + l16;
  short8 qf0 = *(const short8*)(qbase + (size_t)qrow * 1152 + quad * 8);
  short8 qf1 = *(const short8*)(qbase + (size_t)qrow * 1152 + 32 + quad * 8);
  floatx4 O[4];
  float lsum = 0.f;
#pragma unroll
  for (int j = 0; j < 4; j++) O[j] = zero4();

  int r8a = tid >> 3, c8 = (tid & 7) * 8;
  int r8b = r8a + 32;
  short8 rk0, rk1, rv0, rv1;
  rk0 = *(const short8*)(kbase + (size_t)r8a * 1152 + c8);
  rk1 = *(const short8*)(kbase + (size_t)r8b * 1152 + c8);
  rv0 = *(const short8*)(vtb + (size_t)r8a * 2048 + c8);
  rv1 = *(const short8*)(vtb + (size_t)r8b * 2048 + c8);

#pragma unroll 2
  for (int kt = 0; kt < 32; kt++) {
    int cur = kt & 1;
    *(short8*)&Ks[cur][r8a][c8] = rk0;
    *(short8*)&Ks[cur][r8b][c8] = rk1;
    *(short8*)&Vts[cur][r8a][c8] = rv0;
    *(short8*)&Vts[cur][r8b][c8] = rv1;
    __syncthreads();
    if (kt < 31) {
      int key0 = (kt + 1) * 64;
      rk0 = *(const short8*)(kbase + (size_t)(key0 + r8a) * 1152 + c8);
      rk1 = *(const short8*)(kbase + (size_t)(key0 + r8b) * 1152 + c8);
      rv0 = *(const short8*)(vtb + (size_t)r8a * 2048 + key0 + c8);
      rv1 = *(const short8*)(vtb + (size_t)r8b * 2048 + key0 + c8);
    }
    // S^T tiles: st[mt] holds S^T[key=mt*16+quad*4+r][qrow=l16]
#pragma unroll
    for (int mt = 0; mt < 4; mt++) {
      short8 a0 = *(const short8*)&Ks[cur][mt * 16 + l16][quad * 8];
      short8 a1 = *(const short8*)&Ks[cur][mt * 16 + l16][32 + quad * 8];
      floatx4 st = mfma16(a0, qf0, zero4());
      st = mfma16(a1, qf1, st);
      // softmax: p = exp2(s); pack 4 contiguous keys -> one b64 write
      float p0 = exp2f(st[0]), p1 = exp2f(st[1]);
      float p2 = exp2f(st[2]), p3 = exp2f(st[3]);
      lsum += (p0 + p1) + (p2 + p3);
      uint2 pk;
      pk.x = permpack(p0, p1);
      pk.y = permpack(p2, p3);
      *(uint2*)&Ps[wave][l16][mt * 16 + quad * 4] = pk;
    }
    // P^T as B-operand: lane reads its own q-row, keys quad*8+j
    short8 pf0 = *(const short8*)&Ps[wave][l16][quad * 8];
    short8 pf1 = *(const short8*)&Ps[wave][l16][32 + quad * 8];
#pragma unroll
    for (int mt2 = 0; mt2 < 4; mt2++) {
      short8 v0 = *(const short8*)&Vts[cur][mt2 * 16 + l16][quad * 8];
      short8 v1 = *(const short8*)&Vts[cur][mt2 * 16 + l16][32 + quad * 8];
      O[mt2] = mfma16(v0, pf0, O[mt2]);
      O[mt2] = mfma16(v1, pf1, O[mt2]);
    }
  }
  lsum += __shfl_xor(lsum, 16);
  lsum += __shfl_xor(lsum, 32);
  float rl = 1.f / lsum;
  u16* orow = attnpre + (size_t)(b * 2048 + q0 + wave * 16 + l16) * 384 + h * 64;
#pragma unroll
  for (int mt2 = 0; mt2 < 4; mt2++) {
    sh4u pk;
#pragma unroll
    for (int r = 0; r < 4; r++) pk.u[r] = f2b(O[mt2][r] * rl);
    *(sh4v*)(orow + mt2 * 16 + quad * 4) = pk.v;
  }
}

// ---------------- EdgeConv gather (bf16 G|base) + leaky-relu + max over K=8 ----------------
__global__ __launch_bounds__(256) void knn_kernel(const u16* __restrict__ GBb,
                                                  const int* __restrict__ idx,
                                                  const float* __restrict__ bknn,
                                                  u16* __restrict__ outB) {
  int wave = threadIdx.x >> 6, lane = threadIdx.x & 63;
  int row = blockIdx.x * 4 + wave;  // 0..8191
  int b = row >> 11, n = row & 2047;
  float base[6], acc[6];
#pragma unroll
  for (int j = 0; j < 6; j++) {
    int d = lane + 64 * j;
    base[j] = b2f(GBb[(size_t)row * 768 + 384 + d]) + bknn[d];
    acc[j] = -1e30f;
  }
  for (int kk = 0; kk < 8; kk++) {
    int g = idx[(b * 8 + kk) * 2048 + n];
    const u16* Gr = GBb + (size_t)g * 768;
#pragma unroll
    for (int j = 0; j < 6; j++) {
      float v = b2f(Gr[lane + 64 * j]) + base[j];
      v = v > 0.f ? v : 0.2f * v;
      acc[j] = fmaxf(acc[j], v);
    }
  }
#pragma unroll
  for (int j = 0; j < 6; j++)
    outB[(size_t)row * 384 + lane + 64 * j] = f2b(acc[j]);
}

// ---------------- launch ----------------
extern "C" void kernel_launch(void* const* d_in, const int* in_sizes, int n_in,
                              void* d_out, int out_size, void* d_ws, size_t ws_size,
                              hipStream_t stream) {
  const float* x    = (const float*)d_in[0];
  const int* kidx   = (const int*)d_in[1];
  const float* ln1g = (const float*)d_in[2];
  const float* ln1b = (const float*)d_in[3];
  const float* wqkv = (const float*)d_in[4];
  const float* wproj= (const float*)d_in[5];
  const float* bproj= (const float*)d_in[6];
  const float* wknn = (const float*)d_in[7];
  const float* bknn = (const float*)d_in[8];
  const float* wg1  = (const float*)d_in[9];
  const float* bg1  = (const float*)d_in[10];
  const float* wg2  = (const float*)d_in[11];
  const float* bg2  = (const float*)d_in[12];
  const float* ln2g = (const float*)d_in[13];
  const float* ln2b = (const float*)d_in[14];
  const float* wfc1 = (const float*)d_in[15];
  const float* bfc1 = (const float*)d_in[16];
  const float* wfc2 = (const float*)d_in[17];
  const float* bfc2 = (const float*)d_in[18];
  float* out = (float*)d_out;

  const int M = 8192;
  char* ws = (char*)d_ws;
  size_t off = 0;
  auto alloc = [&](size_t bytes) -> char* {
    char* p = ws + off;
    off += (bytes + 255) & ~(size_t)255;
    return p;
  };
  u16* nx_bf    = (u16*)alloc((size_t)M * 384 * 2);
  u16* qkv_bf   = (u16*)alloc((size_t)M * 1152 * 2);   // reused as h_bf after attn
  u16* attnpre  = (u16*)alloc((size_t)M * 384 * 2);
  u16* attn_bf  = (u16*)alloc((size_t)M * 384 * 2);
  u16* GBb      = (u16*)alloc((size_t)M * 768 * 2);    // [G | base] bf16
  u16* knn_bf   = (u16*)alloc((size_t)M * 384 * 2);
  float* x2     = (float*)alloc((size_t)M * 384 * 4);
  u16* t1_bf    = (u16*)alloc((size_t)M * 384 * 2);
  u16* nx2_bf   = (u16*)alloc((size_t)M * 384 * 2);
  u16* Vt_b     = (u16*)alloc((size_t)24 * 64 * 2048 * 2);
  u16* wqkvT    = (u16*)alloc((size_t)1152 * 384 * 2);
  u16* wprojT   = (u16*)alloc(384 * 384 * 2);
  u16* wcT      = (u16*)alloc((size_t)768 * 384 * 2);
  u16* wg1T     = (u16*)alloc((size_t)384 * 768 * 2);
  u16* wg2T     = (u16*)alloc(384 * 384 * 2);
  u16* wfc1T    = (u16*)alloc((size_t)1536 * 384 * 2);
  u16* wfc2T    = (u16*)alloc((size_t)384 * 1536 * 2);
  u16* h_bf     = qkv_bf;  // 8192x1536 bf16 = 25.2 MB over dead qkv+attnpre regions

  // weight prep (one launch)
  tc7_kernel<<<612, 256, 0, stream>>>(wqkv, wproj, wg1, wg2, wfc1, wfc2, wknn,
                                      wqkvT, wprojT, wg1T, wg2T, wfc1T, wfc2T, wcT);
  // LN1
  ln_kernel<<<2048, 256, 0, stream>>>(x, ln1g, ln1b, nx_bf);
  // qkv = nx @ w_qkv -> bf16 (Q pre-scaled, V^T scatter)
  gemm128_kernel<6><<<dim3(9, 64), 256, 0, stream>>>(nx_bf, wqkvT, 1152, 384,
                                                     nullptr, qkv_bf, Vt_b);
  // GBb = nx @ [W1 | W2-W1] -> bf16
  gemm64_kernel<0><<<dim3(12, 128), 256, 0, stream>>>(nx_bf, nx_bf, 384, wcT, 768, 384,
                                                      nullptr, nullptr, GBb,
                                                      nullptr, nullptr, nullptr);
  // attention
  attn1_kernel<<<dim3(32, 24), 256, 0, stream>>>(qkv_bf, Vt_b, attnpre);
  // proj (+b_proj) -> bf16
  gemm64_kernel<2><<<dim3(6, 128), 256, 0, stream>>>(attnpre, attnpre, 384, wprojT, 384, 384,
                                                     bproj, nullptr, attn_bf,
                                                     nullptr, nullptr, nullptr);
  // EdgeConv gather-max
  knn_kernel<<<2048, 256, 0, stream>>>(GBb, kidx, bknn, knn_bf);
  // gate hidden: gelu([attn|knn] @ w_g1 + b_g1) -> bf16
  gemm64_kernel<3><<<dim3(6, 128), 256, 0, stream>>>(attn_bf, knn_bf, 384, wg1T, 384, 768,
                                                     bg1, nullptr, t1_bf,
                                                     nullptr, nullptr, nullptr);
  // gate + fuse + residual: x2 = x + (1-g)*attn + g*knn
  gemm64_kernel<4><<<dim3(6, 128), 256, 0, stream>>>(t1_bf, t1_bf, 384, wg2T, 384, 384,
                                                     bg2, x2, nullptr,
                                                     attn_bf, knn_bf, x);
  // LN2
  ln_kernel<<<2048, 256, 0, stream>>>(x2, ln2g, ln2b, nx2_bf);
  // fc1: gelu(nx2 @ w_fc1 + b_fc1) -> bf16
  gemm128_kernel<3><<<dim3(12, 64), 256, 0, stream>>>(nx2_bf, wfc1T, 1536, 384,
                                                      bfc1, h_bf, nullptr);
  // fc2: out = x2 + h @ w_fc2 + b_fc2
  gemm64_kernel<5><<<dim3(6, 128), 256, 0, stream>>>(h_bf, h_bf, 1536, wfc2T, 384, 1536,
                                                     bfc2, out, nullptr,
                                                     nullptr, nullptr, x2);
  (void)in_sizes; (void)n_in; (void)out_size; (void)ws_size;
}